// Round 1
// baseline (408.120 us; speedup 1.0000x reference)
//
#include <hip/hip_runtime.h>

#define NN 50000
#define EE 800000
#define DD 96
#define GG 64
#define NC 24   // float4 chunks per 96-float row

// ---------------- CSR build ----------------

__global__ void k_init(float* deg, int* counts, int* fill) {
    int i = blockIdx.x * 256 + threadIdx.x;
    if (i < NN) { deg[i] = 1.0f; counts[i] = 0; fill[i] = 0; }
}

__global__ void k_degcount(const int* __restrict__ src, const int* __restrict__ dst,
                           const float* __restrict__ ew, float* deg, int* counts) {
    int e = blockIdx.x * 256 + threadIdx.x;
    if (e < EE) {
        int d = dst[e];
        atomicAdd(&deg[d], ew[e]);
        atomicAdd(&counts[d], 1);
    }
}

__global__ void k_dinv(float* deg) {
    int i = blockIdx.x * 256 + threadIdx.x;
    if (i < NN) deg[i] = rsqrtf(deg[i]);   // deg >= 1 always (self-loop)
}

__global__ void k_reduce(const int* __restrict__ counts, int* bsums) {
    __shared__ int s[256];
    int i = blockIdx.x * 256 + threadIdx.x;
    s[threadIdx.x] = (i < NN) ? counts[i] : 0;
    __syncthreads();
    for (int off = 128; off > 0; off >>= 1) {
        if (threadIdx.x < off) s[threadIdx.x] += s[threadIdx.x + off];
        __syncthreads();
    }
    if (threadIdx.x == 0) bsums[blockIdx.x] = s[0];
}

__global__ void k_scan_bsums(int* bsums, int nb, int* row_ptr) {
    __shared__ int s[256];
    int tid = threadIdx.x;
    int v = (tid < nb) ? bsums[tid] : 0;
    s[tid] = v; __syncthreads();
    for (int off = 1; off < 256; off <<= 1) {
        int t = (tid >= off) ? s[tid - off] : 0;
        __syncthreads();
        s[tid] += t;
        __syncthreads();
    }
    if (tid < nb) bsums[tid] = s[tid] - v;   // exclusive
    if (tid == 0) row_ptr[NN] = EE;
}

__global__ void k_scan_counts(const int* __restrict__ counts, const int* __restrict__ bsums,
                              int* row_ptr) {
    __shared__ int s[256];
    int tid = threadIdx.x;
    int i = blockIdx.x * 256 + tid;
    int v = (i < NN) ? counts[i] : 0;
    s[tid] = v; __syncthreads();
    for (int off = 1; off < 256; off <<= 1) {
        int t = (tid >= off) ? s[tid - off] : 0;
        __syncthreads();
        s[tid] += t;
        __syncthreads();
    }
    if (i < NN) row_ptr[i] = bsums[blockIdx.x] + s[tid] - v;   // exclusive
}

__global__ void k_scatter(const int* __restrict__ src, const int* __restrict__ dst,
                          const float* __restrict__ ew, const float* __restrict__ dinv,
                          const int* __restrict__ row_ptr, int* fill, int2* csr) {
    int e = blockIdx.x * 256 + threadIdx.x;
    if (e < EE) {
        int s = src[e], d = dst[e];
        int p = row_ptr[d] + atomicAdd(&fill[d], 1);
        float w = dinv[s] * ew[e] * dinv[d];
        csr[p] = make_int2(s, __float_as_int(w));
    }
}

// ---------------- GEMMs (f32 vector ALU, W in LDS) ----------------

__device__ __forceinline__ void fma4(float4& a, float s, const float4 w) {
    a.x = fmaf(s, w.x, a.x); a.y = fmaf(s, w.y, a.y);
    a.z = fmaf(s, w.z, a.z); a.w = fmaf(s, w.w, a.w);
}

// T = X @ W   (block: 32 rows x 8 col-groups of 12)
__global__ __launch_bounds__(256) void k_gemm1(const float* __restrict__ X,
                                               const float* __restrict__ W,
                                               float* __restrict__ T) {
    __shared__ float sW[DD * DD];
    int tid = threadIdx.x;
    for (int i = tid; i < DD * DD / 4; i += 256)
        ((float4*)sW)[i] = ((const float4*)W)[i];
    __syncthreads();
    int r = tid >> 3, cg = tid & 7;
    int row = blockIdx.x * 32 + r;
    if (row >= NN) return;
    const float4* xr = (const float4*)(X + (size_t)row * DD);
    float4 a0 = {0,0,0,0}, a1 = {0,0,0,0}, a2 = {0,0,0,0};
    #pragma unroll 4
    for (int k4 = 0; k4 < NC; ++k4) {
        float4 xv = xr[k4];
        #pragma unroll
        for (int kk = 0; kk < 4; ++kk) {
            float xs = kk == 0 ? xv.x : kk == 1 ? xv.y : kk == 2 ? xv.z : xv.w;
            const float4* wr = (const float4*)&sW[(k4 * 4 + kk) * DD + cg * 12];
            fma4(a0, xs, wr[0]); fma4(a1, xs, wr[1]); fma4(a2, xs, wr[2]);
        }
    }
    float4* o = (float4*)(T + (size_t)row * DD + cg * 12);
    o[0] = a0; o[1] = a1; o[2] = a2;
}

// T3 = H @ W3, T4 = H @ W4 fused; T4 may alias H (each block reads only its
// own rows; __syncthreads() before the stores).
__global__ __launch_bounds__(256) void k_gemm2(const float* __restrict__ H,
                                               const float* __restrict__ W3,
                                               const float* __restrict__ W4,
                                               float* __restrict__ T3,
                                               float* __restrict__ T4) {
    __shared__ float sW3[DD * DD];
    __shared__ float sW4[DD * DD];
    int tid = threadIdx.x;
    for (int i = tid; i < DD * DD / 4; i += 256) {
        ((float4*)sW3)[i] = ((const float4*)W3)[i];
        ((float4*)sW4)[i] = ((const float4*)W4)[i];
    }
    __syncthreads();
    int r = tid >> 3, cg = tid & 7;
    int row0 = blockIdx.x * 32 + r;
    int row = row0 < NN ? row0 : NN - 1;   // clamp: keep all threads for barrier
    const float4* xr = (const float4*)(H + (size_t)row * DD);
    float4 a30 = {0,0,0,0}, a31 = {0,0,0,0}, a32 = {0,0,0,0};
    float4 a40 = {0,0,0,0}, a41 = {0,0,0,0}, a42 = {0,0,0,0};
    #pragma unroll 2
    for (int k4 = 0; k4 < NC; ++k4) {
        float4 xv = xr[k4];
        #pragma unroll
        for (int kk = 0; kk < 4; ++kk) {
            float xs = kk == 0 ? xv.x : kk == 1 ? xv.y : kk == 2 ? xv.z : xv.w;
            int k = k4 * 4 + kk;
            const float4* w3 = (const float4*)&sW3[k * DD + cg * 12];
            const float4* w4 = (const float4*)&sW4[k * DD + cg * 12];
            fma4(a30, xs, w3[0]); fma4(a31, xs, w3[1]); fma4(a32, xs, w3[2]);
            fma4(a40, xs, w4[0]); fma4(a41, xs, w4[1]); fma4(a42, xs, w4[2]);
        }
    }
    __syncthreads();   // all reads of H done before T4 (alias of H) is written
    if (row0 < NN) {
        float4* o3 = (float4*)(T3 + (size_t)row * DD + cg * 12);
        o3[0] = a30; o3[1] = a31; o3[2] = a32;
        float4* o4 = (float4*)(T4 + (size_t)row * DD + cg * 12);
        o4[0] = a40; o4[1] = a41; o4[2] = a42;
    }
}

// ---------------- propagation (CSR gather) ----------------
// 192 threads = 8 nodes x 24 float4-chunks

__global__ __launch_bounds__(192) void k_prop_relu(const float* __restrict__ T,
                                                   const int2* __restrict__ csr,
                                                   const int* __restrict__ row_ptr,
                                                   const float* __restrict__ dinv,
                                                   const float* __restrict__ bias,
                                                   float* __restrict__ Hout) {
    int tid = threadIdx.x;
    int node = blockIdx.x * 8 + tid / 24;
    int c = tid % 24;
    if (node >= NN) return;
    const float4* T4v = (const float4*)T;
    float4 b = ((const float4*)bias)[c];
    float di = dinv[node];
    float self = di * di;
    float4 tv = T4v[node * NC + c];
    float4 acc;
    acc.x = fmaf(self, tv.x, b.x); acc.y = fmaf(self, tv.y, b.y);
    acc.z = fmaf(self, tv.z, b.z); acc.w = fmaf(self, tv.w, b.w);
    int e0 = row_ptr[node], e1 = row_ptr[node + 1];
    for (int e = e0; e < e1; ++e) {
        int2 sw = csr[e];
        float w = __int_as_float(sw.y);
        float4 sv = T4v[sw.x * NC + c];
        fma4(acc, w, sv);
    }
    acc.x = fmaxf(acc.x, 0.f); acc.y = fmaxf(acc.y, 0.f);
    acc.z = fmaxf(acc.z, 0.f); acc.w = fmaxf(acc.w, 0.f);
    ((float4*)Hout)[node * NC + c] = acc;
}

__global__ __launch_bounds__(192) void k_prop2(const float* __restrict__ T3,
                                               const float* __restrict__ T4_,
                                               const int2* __restrict__ csr,
                                               const int* __restrict__ row_ptr,
                                               const float* __restrict__ dinv,
                                               const float* __restrict__ b3,
                                               const float* __restrict__ b4,
                                               float* __restrict__ Embed,
                                               float* __restrict__ Ge) {
    int tid = threadIdx.x;
    int node = blockIdx.x * 8 + tid / 24;
    int c = tid % 24;
    if (node >= NN) return;
    const float4* A = (const float4*)T3;
    const float4* B = (const float4*)T4_;
    float4 bv3 = ((const float4*)b3)[c];
    float4 bv4 = ((const float4*)b4)[c];
    float di = dinv[node];
    float self = di * di;
    float4 t3v = A[node * NC + c];
    float4 t4v = B[node * NC + c];
    float4 a3, a4;
    a3.x = fmaf(self, t3v.x, bv3.x); a3.y = fmaf(self, t3v.y, bv3.y);
    a3.z = fmaf(self, t3v.z, bv3.z); a3.w = fmaf(self, t3v.w, bv3.w);
    a4.x = fmaf(self, t4v.x, bv4.x); a4.y = fmaf(self, t4v.y, bv4.y);
    a4.z = fmaf(self, t4v.z, bv4.z); a4.w = fmaf(self, t4v.w, bv4.w);
    int e0 = row_ptr[node], e1 = row_ptr[node + 1];
    for (int e = e0; e < e1; ++e) {
        int2 sw = csr[e];
        float w = __int_as_float(sw.y);
        fma4(a3, w, A[sw.x * NC + c]);
        fma4(a4, w, B[sw.x * NC + c]);
    }
    ((float4*)Embed)[node * NC + c] = a3;
    ((float4*)Ge)[node * NC + c] = a4;
}

// ---------------- global add pool (batch is sorted) ----------------

__global__ __launch_bounds__(384) void k_pool(const float* __restrict__ Ge,
                                              const int* __restrict__ batch,
                                              float* __restrict__ outG) {
    int g = blockIdx.x;
    int tid = threadIdx.x;
    int d = tid % 96, s = tid / 96;
    int lo = 0, hi = NN;
    while (lo < hi) { int m = (lo + hi) >> 1; if (batch[m] < g) lo = m + 1; else hi = m; }
    int start = lo;
    lo = 0; hi = NN;
    while (lo < hi) { int m = (lo + hi) >> 1; if (batch[m] < g + 1) lo = m + 1; else hi = m; }
    int end = lo;
    float acc = 0.f;
    for (int i = start + s; i < end; i += 4) acc += Ge[(size_t)i * DD + d];
    __shared__ float red[384];
    red[tid] = acc;
    __syncthreads();
    if (tid < 96) outG[g * DD + tid] = red[tid] + red[tid + 96] + red[tid + 192] + red[tid + 288];
}

// ---------------- launch ----------------

extern "C" void kernel_launch(void* const* d_in, const int* in_sizes, int n_in,
                              void* d_out, int out_size, void* d_ws, size_t ws_size,
                              hipStream_t stream) {
    const float* x  = (const float*)d_in[0];
    const float* W1 = (const float*)d_in[1];
    const float* b1 = (const float*)d_in[2];
    const float* W3 = (const float*)d_in[3];
    const float* b3 = (const float*)d_in[4];
    const float* W4 = (const float*)d_in[5];
    const float* b4 = (const float*)d_in[6];
    const float* ew = (const float*)d_in[7];
    const int* ei   = (const int*)d_in[8];
    const int* src  = ei;
    const int* dst  = ei + EE;
    const int* batch = (const int*)d_in[9];

    float* out_embed = (float*)d_out;
    float* out_graph = out_embed + (size_t)NN * DD;

    char* w = (char*)d_ws;
    auto alloc = [&](size_t bytes) { char* p = w; w += (bytes + 255) & ~(size_t)255; return p; };
    float* deg     = (float*)alloc((size_t)NN * 4);        // becomes dinv in place
    int*   counts  = (int*)  alloc((size_t)NN * 4);
    int*   fill    = (int*)  alloc((size_t)NN * 4);
    int*   row_ptr = (int*)  alloc((size_t)(NN + 1) * 4);
    int*   bsums   = (int*)  alloc(256 * 4);
    int2*  csr     = (int2*) alloc((size_t)EE * 8);
    float* t1      = (float*)alloc((size_t)NN * DD * 4);
    float* h       = (float*)alloc((size_t)NN * DD * 4);
    float* t3      = (float*)alloc((size_t)NN * DD * 4);
    float* t4 = h;    // gemm2 writes T4 over H (safe: per-block row ownership + barrier)
    float* ge = t1;   // t1 dead after prop1

    int nbN = (NN + 255) / 256;       // 196
    int nbE = (EE + 255) / 256;       // 3125

    k_init<<<nbN, 256, 0, stream>>>(deg, counts, fill);
    k_degcount<<<nbE, 256, 0, stream>>>(src, dst, ew, deg, counts);
    k_dinv<<<nbN, 256, 0, stream>>>(deg);
    k_reduce<<<nbN, 256, 0, stream>>>(counts, bsums);
    k_scan_bsums<<<1, 256, 0, stream>>>(bsums, nbN, row_ptr);
    k_scan_counts<<<nbN, 256, 0, stream>>>(counts, bsums, row_ptr);
    k_scatter<<<nbE, 256, 0, stream>>>(src, dst, ew, deg, row_ptr, fill, csr);

    k_gemm1<<<(NN + 31) / 32, 256, 0, stream>>>(x, W1, t1);
    k_prop_relu<<<(NN + 7) / 8, 192, 0, stream>>>(t1, csr, row_ptr, deg, b1, h);
    k_gemm2<<<(NN + 31) / 32, 256, 0, stream>>>(h, W3, W4, t3, t4);
    k_prop2<<<(NN + 7) / 8, 192, 0, stream>>>(t3, t4, csr, row_ptr, deg, b3, b4, out_embed, ge);
    k_pool<<<GG, 384, 0, stream>>>(ge, batch, out_graph);
}

// Round 2
// 344.278 us; speedup vs baseline: 1.1854x; 1.1854x over previous
//
#include <hip/hip_runtime.h>

#define NN 50000
#define EE 800000
#define DD 96
#define GG 64
#define NC 24   // float4 chunks per 96-float row

// ---------------- CSR build ----------------

__global__ void k_init(float* deg, int* counts, int* fill) {
    int i = blockIdx.x * 256 + threadIdx.x;
    if (i < NN) { deg[i] = 1.0f; counts[i] = 0; fill[i] = 0; }
}

__global__ void k_degcount(const int* __restrict__ src, const int* __restrict__ dst,
                           const float* __restrict__ ew, float* deg, int* counts) {
    int e = blockIdx.x * 256 + threadIdx.x;
    if (e < EE) {
        int d = dst[e];
        atomicAdd(&deg[d], ew[e]);
        atomicAdd(&counts[d], 1);
    }
}

__global__ void k_dinv(float* deg) {
    int i = blockIdx.x * 256 + threadIdx.x;
    if (i < NN) deg[i] = rsqrtf(deg[i]);   // deg >= 1 always (self-loop)
}

__global__ void k_reduce(const int* __restrict__ counts, int* bsums) {
    __shared__ int s[256];
    int i = blockIdx.x * 256 + threadIdx.x;
    s[threadIdx.x] = (i < NN) ? counts[i] : 0;
    __syncthreads();
    for (int off = 128; off > 0; off >>= 1) {
        if (threadIdx.x < off) s[threadIdx.x] += s[threadIdx.x + off];
        __syncthreads();
    }
    if (threadIdx.x == 0) bsums[blockIdx.x] = s[0];
}

__global__ void k_scan_bsums(int* bsums, int nb, int* row_ptr) {
    __shared__ int s[256];
    int tid = threadIdx.x;
    int v = (tid < nb) ? bsums[tid] : 0;
    s[tid] = v; __syncthreads();
    for (int off = 1; off < 256; off <<= 1) {
        int t = (tid >= off) ? s[tid - off] : 0;
        __syncthreads();
        s[tid] += t;
        __syncthreads();
    }
    if (tid < nb) bsums[tid] = s[tid] - v;   // exclusive
    if (tid == 0) row_ptr[NN] = EE;
}

__global__ void k_scan_counts(const int* __restrict__ counts, const int* __restrict__ bsums,
                              int* row_ptr) {
    __shared__ int s[256];
    int tid = threadIdx.x;
    int i = blockIdx.x * 256 + tid;
    int v = (i < NN) ? counts[i] : 0;
    s[tid] = v; __syncthreads();
    for (int off = 1; off < 256; off <<= 1) {
        int t = (tid >= off) ? s[tid - off] : 0;
        __syncthreads();
        s[tid] += t;
        __syncthreads();
    }
    if (i < NN) row_ptr[i] = bsums[blockIdx.x] + s[tid] - v;   // exclusive
}

__global__ void k_scatter(const int* __restrict__ src, const int* __restrict__ dst,
                          const float* __restrict__ ew, const float* __restrict__ dinv,
                          const int* __restrict__ row_ptr, int* fill, int2* csr) {
    int e = blockIdx.x * 256 + threadIdx.x;
    if (e < EE) {
        int s = src[e], d = dst[e];
        int p = row_ptr[d] + atomicAdd(&fill[d], 1);
        float w = dinv[s] * ew[e] * dinv[d];
        csr[p] = make_int2(s, __float_as_int(w));
    }
}

// ---------------- propagation (CSR gather): P = A_hat * T ----------------
// 192 threads = 8 nodes x 24 float4-chunks. No bias (folded into GEMM after).

__device__ __forceinline__ void fma4(float4& a, float s, const float4 w) {
    a.x = fmaf(s, w.x, a.x); a.y = fmaf(s, w.y, a.y);
    a.z = fmaf(s, w.z, a.z); a.w = fmaf(s, w.w, a.w);
}

__global__ __launch_bounds__(192) void k_prop(const float* __restrict__ T,
                                              const int2* __restrict__ csr,
                                              const int* __restrict__ row_ptr,
                                              const float* __restrict__ dinv,
                                              float* __restrict__ P) {
    int tid = threadIdx.x;
    int node = blockIdx.x * 8 + tid / 24;
    int c = tid % 24;
    if (node >= NN) return;
    const float4* T4v = (const float4*)T;
    float di = dinv[node];
    float self = di * di;
    float4 tv = T4v[node * NC + c];
    float4 acc = make_float4(self * tv.x, self * tv.y, self * tv.z, self * tv.w);
    int e0 = row_ptr[node], e1 = row_ptr[node + 1];
    for (int e = e0; e < e1; ++e) {
        int2 sw = csr[e];
        float w = __int_as_float(sw.y);
        fma4(acc, w, T4v[sw.x * NC + c]);
    }
    ((float4*)P)[node * NC + c] = acc;
}

// ---------------- GEMM: O = act(X @ W + b)  (W in LDS) ----------------
// block: 32 rows x 8 col-groups of 12

template<bool RELU>
__global__ __launch_bounds__(256) void k_gemm_bias(const float* __restrict__ X,
                                                   const float* __restrict__ W,
                                                   const float* __restrict__ bias,
                                                   float* __restrict__ O) {
    __shared__ float sW[DD * DD];
    int tid = threadIdx.x;
    for (int i = tid; i < DD * DD / 4; i += 256)
        ((float4*)sW)[i] = ((const float4*)W)[i];
    __syncthreads();
    int r = tid >> 3, cg = tid & 7;
    int row = blockIdx.x * 32 + r;
    if (row >= NN) return;
    const float4* xr = (const float4*)(X + (size_t)row * DD);
    const float4* bv = (const float4*)(bias) + cg * 3;
    float4 a0 = bv[0], a1 = bv[1], a2 = bv[2];
    #pragma unroll 4
    for (int k4 = 0; k4 < NC; ++k4) {
        float4 xv = xr[k4];
        #pragma unroll
        for (int kk = 0; kk < 4; ++kk) {
            float xs = kk == 0 ? xv.x : kk == 1 ? xv.y : kk == 2 ? xv.z : xv.w;
            const float4* wr = (const float4*)&sW[(k4 * 4 + kk) * DD + cg * 12];
            fma4(a0, xs, wr[0]); fma4(a1, xs, wr[1]); fma4(a2, xs, wr[2]);
        }
    }
    if (RELU) {
        a0.x = fmaxf(a0.x, 0.f); a0.y = fmaxf(a0.y, 0.f); a0.z = fmaxf(a0.z, 0.f); a0.w = fmaxf(a0.w, 0.f);
        a1.x = fmaxf(a1.x, 0.f); a1.y = fmaxf(a1.y, 0.f); a1.z = fmaxf(a1.z, 0.f); a1.w = fmaxf(a1.w, 0.f);
        a2.x = fmaxf(a2.x, 0.f); a2.y = fmaxf(a2.y, 0.f); a2.z = fmaxf(a2.z, 0.f); a2.w = fmaxf(a2.w, 0.f);
    }
    float4* o = (float4*)(O + (size_t)row * DD + cg * 12);
    o[0] = a0; o[1] = a1; o[2] = a2;
}

// ---------------- fused pool + W4 projection ----------------
// out_graph[g] = (sum_{i in g} P2[i]) @ W4 + count_g * b4
// batch is sorted; one block per graph. 384 threads = 4 stripes x 96 dims.

__global__ __launch_bounds__(384) void k_pool(const float* __restrict__ P2,
                                              const int* __restrict__ batch,
                                              const float* __restrict__ W4,
                                              const float* __restrict__ b4,
                                              float* __restrict__ outG) {
    int g = blockIdx.x;
    int tid = threadIdx.x;
    int d = tid % 96, s = tid / 96;
    int lo = 0, hi = NN;
    while (lo < hi) { int m = (lo + hi) >> 1; if (batch[m] < g) lo = m + 1; else hi = m; }
    int start = lo;
    lo = 0; hi = NN;
    while (lo < hi) { int m = (lo + hi) >> 1; if (batch[m] < g + 1) lo = m + 1; else hi = m; }
    int end = lo;
    float acc = 0.f;
    for (int i = start + s; i < end; i += 4) acc += P2[(size_t)i * DD + d];
    __shared__ float red[384];
    __shared__ float srow[96];
    red[tid] = acc;
    __syncthreads();
    if (tid < 96) srow[tid] = red[tid] + red[tid + 96] + red[tid + 192] + red[tid + 288];
    __syncthreads();
    if (tid < 96) {
        float o = (float)(end - start) * b4[tid];
        #pragma unroll 8
        for (int k = 0; k < 96; ++k) o = fmaf(srow[k], W4[k * 96 + tid], o);
        outG[g * 96 + tid] = o;
    }
}

// ---------------- launch ----------------

extern "C" void kernel_launch(void* const* d_in, const int* in_sizes, int n_in,
                              void* d_out, int out_size, void* d_ws, size_t ws_size,
                              hipStream_t stream) {
    const float* x  = (const float*)d_in[0];
    const float* W1 = (const float*)d_in[1];
    const float* b1 = (const float*)d_in[2];
    const float* W3 = (const float*)d_in[3];
    const float* b3 = (const float*)d_in[4];
    const float* W4 = (const float*)d_in[5];
    const float* b4 = (const float*)d_in[6];
    const float* ew = (const float*)d_in[7];
    const int* ei   = (const int*)d_in[8];
    const int* src  = ei;
    const int* dst  = ei + EE;
    const int* batch = (const int*)d_in[9];

    float* out_embed = (float*)d_out;
    float* out_graph = out_embed + (size_t)NN * DD;

    char* w = (char*)d_ws;
    auto alloc = [&](size_t bytes) { char* p = w; w += (bytes + 255) & ~(size_t)255; return p; };
    float* deg     = (float*)alloc((size_t)NN * 4);        // becomes dinv in place
    int*   counts  = (int*)  alloc((size_t)NN * 4);
    int*   fill    = (int*)  alloc((size_t)NN * 4);
    int*   row_ptr = (int*)  alloc((size_t)(NN + 1) * 4);
    int*   bsums   = (int*)  alloc(256 * 4);
    int2*  csr     = (int2*) alloc((size_t)EE * 8);
    float* p1      = (float*)alloc((size_t)NN * DD * 4);   // A_hat @ x, then reused as P2
    float* h       = (float*)alloc((size_t)NN * DD * 4);   // relu(p1 @ W1 + b1)
    float* p2 = p1;   // p1 dead after gemm_relu; prop_h writes here

    int nbN = (NN + 255) / 256;       // 196
    int nbE = (EE + 255) / 256;       // 3125

    k_init<<<nbN, 256, 0, stream>>>(deg, counts, fill);
    k_degcount<<<nbE, 256, 0, stream>>>(src, dst, ew, deg, counts);
    k_dinv<<<nbN, 256, 0, stream>>>(deg);
    k_reduce<<<nbN, 256, 0, stream>>>(counts, bsums);
    k_scan_bsums<<<1, 256, 0, stream>>>(bsums, nbN, row_ptr);
    k_scan_counts<<<nbN, 256, 0, stream>>>(counts, bsums, row_ptr);
    k_scatter<<<nbE, 256, 0, stream>>>(src, dst, ew, deg, row_ptr, fill, csr);

    // P1 = A_hat @ x ; h = relu(P1 @ W1 + b1)
    k_prop<<<(NN + 7) / 8, 192, 0, stream>>>(x, csr, row_ptr, deg, p1);
    k_gemm_bias<true><<<(NN + 31) / 32, 256, 0, stream>>>(p1, W1, b1, h);
    // P2 = A_hat @ h ; embed = P2 @ W3 + b3
    k_prop<<<(NN + 7) / 8, 192, 0, stream>>>(h, csr, row_ptr, deg, p2);
    k_gemm_bias<false><<<(NN + 31) / 32, 256, 0, stream>>>(p2, W3, b3, out_embed);
    // out_graph = pool(P2) @ W4 + cnt * b4
    k_pool<<<GG, 384, 0, stream>>>(p2, batch, W4, b4, out_graph);
}

// Round 3
// 278.365 us; speedup vs baseline: 1.4661x; 1.2368x over previous
//
#include <hip/hip_runtime.h>

#define NN 50000
#define EE 800000
#define DD 96
#define GG 64
#define NC 24   // float4 chunks per 96-float row

#define FPSCALE 16777216.0f           // 2^24 fixed-point for weight sums
#define MASK44 ((1ULL << 44) - 1)

// ---------------- CSR build ----------------
// One u64 atomic per edge: high 20 bits = count, low 44 bits = sum(w * 2^24).
// The returned old count is this edge's rank within its dst bucket -> the
// scatter pass needs no atomics at all.

__global__ void k_hist(const int* __restrict__ dst, const float* __restrict__ ew,
                       unsigned long long* packed, unsigned int* rank) {
    int e = blockIdx.x * 256 + threadIdx.x;
    if (e < EE) {
        unsigned long long q = (unsigned long long)(ew[e] * FPSCALE + 0.5f);
        unsigned long long old = atomicAdd(&packed[dst[e]], (1ULL << 44) | q);
        rank[e] = (unsigned int)(old >> 44);
    }
}

__global__ void k_dinv(const unsigned long long* __restrict__ packed, float* dinv) {
    int i = blockIdx.x * 256 + threadIdx.x;
    if (i < NN) {
        float s = (float)(packed[i] & MASK44) * (1.0f / FPSCALE);
        dinv[i] = rsqrtf(1.0f + s);   // self-loop weight 1.0 included
    }
}

__global__ void k_reduce(const unsigned long long* __restrict__ packed, int* bsums) {
    __shared__ int s[256];
    int i = blockIdx.x * 256 + threadIdx.x;
    s[threadIdx.x] = (i < NN) ? (int)(packed[i] >> 44) : 0;
    __syncthreads();
    for (int off = 128; off > 0; off >>= 1) {
        if (threadIdx.x < off) s[threadIdx.x] += s[threadIdx.x + off];
        __syncthreads();
    }
    if (threadIdx.x == 0) bsums[blockIdx.x] = s[0];
}

__global__ void k_scan_bsums(int* bsums, int nb, int* row_ptr) {
    __shared__ int s[256];
    int tid = threadIdx.x;
    int v = (tid < nb) ? bsums[tid] : 0;
    s[tid] = v; __syncthreads();
    for (int off = 1; off < 256; off <<= 1) {
        int t = (tid >= off) ? s[tid - off] : 0;
        __syncthreads();
        s[tid] += t;
        __syncthreads();
    }
    if (tid < nb) bsums[tid] = s[tid] - v;   // exclusive
    if (tid == 0) row_ptr[NN] = EE;
}

__global__ void k_scan_counts(const unsigned long long* __restrict__ packed,
                              const int* __restrict__ bsums, int* row_ptr) {
    __shared__ int s[256];
    int tid = threadIdx.x;
    int i = blockIdx.x * 256 + tid;
    int v = (i < NN) ? (int)(packed[i] >> 44) : 0;
    s[tid] = v; __syncthreads();
    for (int off = 1; off < 256; off <<= 1) {
        int t = (tid >= off) ? s[tid - off] : 0;
        __syncthreads();
        s[tid] += t;
        __syncthreads();
    }
    if (i < NN) row_ptr[i] = bsums[blockIdx.x] + s[tid] - v;   // exclusive
}

__global__ void k_scatter(const int* __restrict__ src, const int* __restrict__ dst,
                          const float* __restrict__ ew, const float* __restrict__ dinv,
                          const int* __restrict__ row_ptr,
                          const unsigned int* __restrict__ rank, int2* csr) {
    int e = blockIdx.x * 256 + threadIdx.x;
    if (e < EE) {
        int s = src[e], d = dst[e];
        int p = row_ptr[d] + (int)rank[e];
        float w = dinv[s] * ew[e] * dinv[d];
        csr[p] = make_int2(s, __float_as_int(w));
    }
}

// ---------------- propagation (CSR gather): P = A_hat * T ----------------
// 192 threads = 8 nodes x 24 float4-chunks. No bias (folded into GEMM after).

__device__ __forceinline__ void fma4(float4& a, float s, const float4 w) {
    a.x = fmaf(s, w.x, a.x); a.y = fmaf(s, w.y, a.y);
    a.z = fmaf(s, w.z, a.z); a.w = fmaf(s, w.w, a.w);
}

__global__ __launch_bounds__(192) void k_prop(const float* __restrict__ T,
                                              const int2* __restrict__ csr,
                                              const int* __restrict__ row_ptr,
                                              const float* __restrict__ dinv,
                                              float* __restrict__ P) {
    int tid = threadIdx.x;
    int node = blockIdx.x * 8 + tid / 24;
    int c = tid % 24;
    if (node >= NN) return;
    const float4* T4v = (const float4*)T;
    float di = dinv[node];
    float self = di * di;
    float4 tv = T4v[node * NC + c];
    float4 acc = make_float4(self * tv.x, self * tv.y, self * tv.z, self * tv.w);
    int e0 = row_ptr[node], e1 = row_ptr[node + 1];
    for (int e = e0; e < e1; ++e) {
        int2 sw = csr[e];
        float w = __int_as_float(sw.y);
        fma4(acc, w, T4v[sw.x * NC + c]);
    }
    ((float4*)P)[node * NC + c] = acc;
}

// ---------------- GEMM: O = act(X @ W + b)  (W in LDS) ----------------
// 256 threads; each thread: 4 rows x 12 cols (amortizes LDS W reads 4x).
// Block covers 128 rows.

template<bool RELU>
__global__ __launch_bounds__(256) void k_gemm_bias(const float* __restrict__ X,
                                                   const float* __restrict__ W,
                                                   const float* __restrict__ bias,
                                                   float* __restrict__ O) {
    __shared__ float sW[DD * DD];
    int tid = threadIdx.x;
    for (int i = tid; i < DD * DD / 4; i += 256)
        ((float4*)sW)[i] = ((const float4*)W)[i];
    __syncthreads();
    int cg = tid & 7, s = tid >> 3;
    int base = blockIdx.x * 128;
    const float4* bv = (const float4*)bias + cg * 3;
    const float4* xr0; const float4* xr1; const float4* xr2; const float4* xr3;
    {
        int r0 = base + s;        int c0 = r0 < NN ? r0 : NN - 1;
        int r1 = base + s + 32;   int c1 = r1 < NN ? r1 : NN - 1;
        int r2 = base + s + 64;   int c2 = r2 < NN ? r2 : NN - 1;
        int r3 = base + s + 96;   int c3 = r3 < NN ? r3 : NN - 1;
        xr0 = (const float4*)(X + (size_t)c0 * DD);
        xr1 = (const float4*)(X + (size_t)c1 * DD);
        xr2 = (const float4*)(X + (size_t)c2 * DD);
        xr3 = (const float4*)(X + (size_t)c3 * DD);
    }
    float4 acc[4][3];
    #pragma unroll
    for (int j = 0; j < 4; ++j) { acc[j][0] = bv[0]; acc[j][1] = bv[1]; acc[j][2] = bv[2]; }

    #pragma unroll 2
    for (int k4 = 0; k4 < NC; ++k4) {
        float4 xv0 = xr0[k4], xv1 = xr1[k4], xv2 = xr2[k4], xv3 = xr3[k4];
        #pragma unroll
        for (int kk = 0; kk < 4; ++kk) {
            const float4* wr = (const float4*)&sW[(k4 * 4 + kk) * DD + cg * 12];
            float4 w0 = wr[0], w1 = wr[1], w2 = wr[2];
            float s0 = kk == 0 ? xv0.x : kk == 1 ? xv0.y : kk == 2 ? xv0.z : xv0.w;
            float s1 = kk == 0 ? xv1.x : kk == 1 ? xv1.y : kk == 2 ? xv1.z : xv1.w;
            float s2 = kk == 0 ? xv2.x : kk == 1 ? xv2.y : kk == 2 ? xv2.z : xv2.w;
            float s3 = kk == 0 ? xv3.x : kk == 1 ? xv3.y : kk == 2 ? xv3.z : xv3.w;
            fma4(acc[0][0], s0, w0); fma4(acc[0][1], s0, w1); fma4(acc[0][2], s0, w2);
            fma4(acc[1][0], s1, w0); fma4(acc[1][1], s1, w1); fma4(acc[1][2], s1, w2);
            fma4(acc[2][0], s2, w0); fma4(acc[2][1], s2, w1); fma4(acc[2][2], s2, w2);
            fma4(acc[3][0], s3, w0); fma4(acc[3][1], s3, w1); fma4(acc[3][2], s3, w2);
        }
    }
    #pragma unroll
    for (int j = 0; j < 4; ++j) {
        int row = base + s + 32 * j;
        if (row >= NN) continue;
        float4 a0 = acc[j][0], a1 = acc[j][1], a2 = acc[j][2];
        if (RELU) {
            a0.x = fmaxf(a0.x, 0.f); a0.y = fmaxf(a0.y, 0.f); a0.z = fmaxf(a0.z, 0.f); a0.w = fmaxf(a0.w, 0.f);
            a1.x = fmaxf(a1.x, 0.f); a1.y = fmaxf(a1.y, 0.f); a1.z = fmaxf(a1.z, 0.f); a1.w = fmaxf(a1.w, 0.f);
            a2.x = fmaxf(a2.x, 0.f); a2.y = fmaxf(a2.y, 0.f); a2.z = fmaxf(a2.z, 0.f); a2.w = fmaxf(a2.w, 0.f);
        }
        float4* o = (float4*)(O + (size_t)row * DD + cg * 12);
        o[0] = a0; o[1] = a1; o[2] = a2;
    }
}

// ---------------- fused pool + W4 projection ----------------
// out_graph[g] = (sum_{i in g} P2[i]) @ W4 + count_g * b4

__global__ __launch_bounds__(384) void k_pool(const float* __restrict__ P2,
                                              const int* __restrict__ batch,
                                              const float* __restrict__ W4,
                                              const float* __restrict__ b4,
                                              float* __restrict__ outG) {
    int g = blockIdx.x;
    int tid = threadIdx.x;
    int d = tid % 96, s = tid / 96;
    int lo = 0, hi = NN;
    while (lo < hi) { int m = (lo + hi) >> 1; if (batch[m] < g) lo = m + 1; else hi = m; }
    int start = lo;
    lo = 0; hi = NN;
    while (lo < hi) { int m = (lo + hi) >> 1; if (batch[m] < g + 1) lo = m + 1; else hi = m; }
    int end = lo;
    float acc = 0.f;
    for (int i = start + s; i < end; i += 4) acc += P2[(size_t)i * DD + d];
    __shared__ float red[384];
    __shared__ float srow[96];
    red[tid] = acc;
    __syncthreads();
    if (tid < 96) srow[tid] = red[tid] + red[tid + 96] + red[tid + 192] + red[tid + 288];
    __syncthreads();
    if (tid < 96) {
        float o = (float)(end - start) * b4[tid];
        #pragma unroll 8
        for (int k = 0; k < 96; ++k) o = fmaf(srow[k], W4[k * 96 + tid], o);
        outG[g * 96 + tid] = o;
    }
}

// ---------------- launch ----------------

extern "C" void kernel_launch(void* const* d_in, const int* in_sizes, int n_in,
                              void* d_out, int out_size, void* d_ws, size_t ws_size,
                              hipStream_t stream) {
    const float* x  = (const float*)d_in[0];
    const float* W1 = (const float*)d_in[1];
    const float* b1 = (const float*)d_in[2];
    const float* W3 = (const float*)d_in[3];
    const float* b3 = (const float*)d_in[4];
    const float* W4 = (const float*)d_in[5];
    const float* b4 = (const float*)d_in[6];
    const float* ew = (const float*)d_in[7];
    const int* ei   = (const int*)d_in[8];
    const int* src  = ei;
    const int* dst  = ei + EE;
    const int* batch = (const int*)d_in[9];

    float* out_embed = (float*)d_out;
    float* out_graph = out_embed + (size_t)NN * DD;

    char* w = (char*)d_ws;
    auto alloc = [&](size_t bytes) { char* p = w; w += (bytes + 255) & ~(size_t)255; return p; };
    unsigned long long* packed = (unsigned long long*)alloc((size_t)NN * 8);
    unsigned int* rank = (unsigned int*)alloc((size_t)EE * 4);
    float* dinv    = (float*)alloc((size_t)NN * 4);
    int*   row_ptr = (int*)  alloc((size_t)(NN + 1) * 4);
    int*   bsums   = (int*)  alloc(256 * 4);
    int2*  csr     = (int2*) alloc((size_t)EE * 8);
    float* p1      = (float*)alloc((size_t)NN * DD * 4);   // A_hat @ x, then reused as P2
    float* h       = (float*)alloc((size_t)NN * DD * 4);   // relu(p1 @ W1 + b1)
    float* p2 = p1;   // p1 dead after first gemm; prop(h) writes here

    int nbN = (NN + 255) / 256;       // 196
    int nbE = (EE + 255) / 256;       // 3125

    hipMemsetAsync(packed, 0, (size_t)NN * 8, stream);
    k_hist<<<nbE, 256, 0, stream>>>(dst, ew, packed, rank);
    k_dinv<<<nbN, 256, 0, stream>>>(packed, dinv);
    k_reduce<<<nbN, 256, 0, stream>>>(packed, bsums);
    k_scan_bsums<<<1, 256, 0, stream>>>(bsums, nbN, row_ptr);
    k_scan_counts<<<nbN, 256, 0, stream>>>(packed, bsums, row_ptr);
    k_scatter<<<nbE, 256, 0, stream>>>(src, dst, ew, dinv, row_ptr, rank, csr);

    // P1 = A_hat @ x ; h = relu(P1 @ W1 + b1)
    k_prop<<<(NN + 7) / 8, 192, 0, stream>>>(x, csr, row_ptr, dinv, p1);
    k_gemm_bias<true><<<(NN + 127) / 128, 256, 0, stream>>>(p1, W1, b1, h);
    // P2 = A_hat @ h ; embed = P2 @ W3 + b3
    k_prop<<<(NN + 7) / 8, 192, 0, stream>>>(h, csr, row_ptr, dinv, p2);
    k_gemm_bias<false><<<(NN + 127) / 128, 256, 0, stream>>>(p2, W3, b3, out_embed);
    // out_graph = pool(P2) @ W4 + cnt * b4
    k_pool<<<GG, 384, 0, stream>>>(p2, batch, W4, b4, out_graph);
}

// Round 4
// 218.261 us; speedup vs baseline: 1.8699x; 1.2754x over previous
//
#include <hip/hip_runtime.h>
#include <hip/hip_fp16.h>

#define NN 50000
#define EE 800000
#define DD 96
#define GG 64
#define NC 24    // float4 chunks per 96-float row
#define NH 12    // uint4 (8-half) chunks per 96-half row

#define FPSCALE 16777216.0f           // 2^24 fixed-point for weight sums
#define MASK44 ((1ULL << 44) - 1)

// ---------------- CSR build ----------------
// One u64 atomic per edge: high 20 bits = count, low 44 bits = sum(w * 2^24).
// The returned old count is this edge's rank within its dst bucket -> the
// scatter pass needs no atomics at all.

__global__ void k_hist(const int* __restrict__ dst, const float* __restrict__ ew,
                       unsigned long long* packed, unsigned int* rank) {
    int e = blockIdx.x * 256 + threadIdx.x;
    if (e < EE) {
        unsigned long long q = (unsigned long long)(ew[e] * FPSCALE + 0.5f);
        unsigned long long old = atomicAdd(&packed[dst[e]], (1ULL << 44) | q);
        rank[e] = (unsigned int)(old >> 44);
    }
}

__global__ void k_dinv(const unsigned long long* __restrict__ packed, float* dinv) {
    int i = blockIdx.x * 256 + threadIdx.x;
    if (i < NN) {
        float s = (float)(packed[i] & MASK44) * (1.0f / FPSCALE);
        dinv[i] = rsqrtf(1.0f + s);   // self-loop weight 1.0 included
    }
}

__global__ void k_reduce(const unsigned long long* __restrict__ packed, int* bsums) {
    __shared__ int s[256];
    int i = blockIdx.x * 256 + threadIdx.x;
    s[threadIdx.x] = (i < NN) ? (int)(packed[i] >> 44) : 0;
    __syncthreads();
    for (int off = 128; off > 0; off >>= 1) {
        if (threadIdx.x < off) s[threadIdx.x] += s[threadIdx.x + off];
        __syncthreads();
    }
    if (threadIdx.x == 0) bsums[blockIdx.x] = s[0];
}

__global__ void k_scan_bsums(int* bsums, int nb, int* row_ptr) {
    __shared__ int s[256];
    int tid = threadIdx.x;
    int v = (tid < nb) ? bsums[tid] : 0;
    s[tid] = v; __syncthreads();
    for (int off = 1; off < 256; off <<= 1) {
        int t = (tid >= off) ? s[tid - off] : 0;
        __syncthreads();
        s[tid] += t;
        __syncthreads();
    }
    if (tid < nb) bsums[tid] = s[tid] - v;   // exclusive
    if (tid == 0) row_ptr[NN] = EE;
}

__global__ void k_scan_counts(const unsigned long long* __restrict__ packed,
                              const int* __restrict__ bsums, int* row_ptr) {
    __shared__ int s[256];
    int tid = threadIdx.x;
    int i = blockIdx.x * 256 + tid;
    int v = (i < NN) ? (int)(packed[i] >> 44) : 0;
    s[tid] = v; __syncthreads();
    for (int off = 1; off < 256; off <<= 1) {
        int t = (tid >= off) ? s[tid - off] : 0;
        __syncthreads();
        s[tid] += t;
        __syncthreads();
    }
    if (i < NN) row_ptr[i] = bsums[blockIdx.x] + s[tid] - v;   // exclusive
}

__global__ void k_scatter(const int* __restrict__ src, const int* __restrict__ dst,
                          const float* __restrict__ ew, const float* __restrict__ dinv,
                          const int* __restrict__ row_ptr,
                          const unsigned int* __restrict__ rank, int2* csr) {
    int e = blockIdx.x * 256 + threadIdx.x;
    if (e < EE) {
        int s = src[e], d = dst[e];
        int p = row_ptr[d] + (int)rank[e];
        float w = dinv[s] * ew[e] * dinv[d];
        csr[p] = make_int2(s, __float_as_int(w));
    }
}

// ---------------- f32 -> fp16 table conversion ----------------

__global__ void k_f2h(const float4* __restrict__ in, uint4* __restrict__ out) {
    int i = blockIdx.x * 256 + threadIdx.x;
    if (i >= NN * DD / 8) return;
    float4 f0 = in[2 * i], f1 = in[2 * i + 1];
    __half2 h0 = __floats2half2_rn(f0.x, f0.y);
    __half2 h1 = __floats2half2_rn(f0.z, f0.w);
    __half2 h2 = __floats2half2_rn(f1.x, f1.y);
    __half2 h3 = __floats2half2_rn(f1.z, f1.w);
    uint4 o;
    o.x = *(unsigned int*)&h0; o.y = *(unsigned int*)&h1;
    o.z = *(unsigned int*)&h2; o.w = *(unsigned int*)&h3;
    out[i] = o;
}

// ---------------- propagation (CSR gather, fp16 rows): P = A_hat * T ----------------
// 192 threads = 16 nodes x 12 chunks of 8 halves. f32 accumulate, f32 output.

__device__ __forceinline__ void cvt8(uint4 v, float* f) {
    const __half2* h = (const __half2*)&v;
    #pragma unroll
    for (int k = 0; k < 4; ++k) {
        float2 t = __half22float2(h[k]);
        f[2 * k] = t.x; f[2 * k + 1] = t.y;
    }
}

__global__ __launch_bounds__(192) void k_prop_h(const uint4* __restrict__ Th,
                                                const int2* __restrict__ csr,
                                                const int* __restrict__ row_ptr,
                                                const float* __restrict__ dinv,
                                                float* __restrict__ P) {
    int tid = threadIdx.x;
    int node = blockIdx.x * 16 + tid / 12;
    int c = tid % 12;
    if (node >= NN) return;
    float di = dinv[node];
    float self = di * di;
    float f[8], acc[8];
    cvt8(Th[node * NH + c], f);
    #pragma unroll
    for (int j = 0; j < 8; ++j) acc[j] = self * f[j];
    int e0 = row_ptr[node], e1 = row_ptr[node + 1];
    for (int e = e0; e < e1; ++e) {
        int2 sw = csr[e];
        float w = __int_as_float(sw.y);
        cvt8(Th[sw.x * NH + c], f);
        #pragma unroll
        for (int j = 0; j < 8; ++j) acc[j] = fmaf(w, f[j], acc[j]);
    }
    float4* o = (float4*)(P + (size_t)node * DD + c * 8);
    o[0] = make_float4(acc[0], acc[1], acc[2], acc[3]);
    o[1] = make_float4(acc[4], acc[5], acc[6], acc[7]);
}

// ---------------- GEMM: O = act(X @ W + b)  (W in LDS) ----------------
// 256 threads; each thread: 4 rows x 12 cols. Block covers 128 rows.
// MODE 0: relu, fp16 output. MODE 1: plain, f32 output.

__device__ __forceinline__ void fma4(float4& a, float s, const float4 w) {
    a.x = fmaf(s, w.x, a.x); a.y = fmaf(s, w.y, a.y);
    a.z = fmaf(s, w.z, a.z); a.w = fmaf(s, w.w, a.w);
}

template<int MODE>
__global__ __launch_bounds__(256) void k_gemm_bias(const float* __restrict__ X,
                                                   const float* __restrict__ W,
                                                   const float* __restrict__ bias,
                                                   float* __restrict__ O,
                                                   __half2* __restrict__ Oh) {
    __shared__ float sW[DD * DD];
    int tid = threadIdx.x;
    for (int i = tid; i < DD * DD / 4; i += 256)
        ((float4*)sW)[i] = ((const float4*)W)[i];
    __syncthreads();
    int cg = tid & 7, s = tid >> 3;
    int base = blockIdx.x * 128;
    const float4* bv = (const float4*)bias + cg * 3;
    const float4* xr0; const float4* xr1; const float4* xr2; const float4* xr3;
    {
        int r0 = base + s;        int c0 = r0 < NN ? r0 : NN - 1;
        int r1 = base + s + 32;   int c1 = r1 < NN ? r1 : NN - 1;
        int r2 = base + s + 64;   int c2 = r2 < NN ? r2 : NN - 1;
        int r3 = base + s + 96;   int c3 = r3 < NN ? r3 : NN - 1;
        xr0 = (const float4*)(X + (size_t)c0 * DD);
        xr1 = (const float4*)(X + (size_t)c1 * DD);
        xr2 = (const float4*)(X + (size_t)c2 * DD);
        xr3 = (const float4*)(X + (size_t)c3 * DD);
    }
    float4 acc[4][3];
    #pragma unroll
    for (int j = 0; j < 4; ++j) { acc[j][0] = bv[0]; acc[j][1] = bv[1]; acc[j][2] = bv[2]; }

    #pragma unroll 2
    for (int k4 = 0; k4 < NC; ++k4) {
        float4 xv0 = xr0[k4], xv1 = xr1[k4], xv2 = xr2[k4], xv3 = xr3[k4];
        #pragma unroll
        for (int kk = 0; kk < 4; ++kk) {
            const float4* wr = (const float4*)&sW[(k4 * 4 + kk) * DD + cg * 12];
            float4 w0 = wr[0], w1 = wr[1], w2 = wr[2];
            float s0 = kk == 0 ? xv0.x : kk == 1 ? xv0.y : kk == 2 ? xv0.z : xv0.w;
            float s1 = kk == 0 ? xv1.x : kk == 1 ? xv1.y : kk == 2 ? xv1.z : xv1.w;
            float s2 = kk == 0 ? xv2.x : kk == 1 ? xv2.y : kk == 2 ? xv2.z : xv2.w;
            float s3 = kk == 0 ? xv3.x : kk == 1 ? xv3.y : kk == 2 ? xv3.z : xv3.w;
            fma4(acc[0][0], s0, w0); fma4(acc[0][1], s0, w1); fma4(acc[0][2], s0, w2);
            fma4(acc[1][0], s1, w0); fma4(acc[1][1], s1, w1); fma4(acc[1][2], s1, w2);
            fma4(acc[2][0], s2, w0); fma4(acc[2][1], s2, w1); fma4(acc[2][2], s2, w2);
            fma4(acc[3][0], s3, w0); fma4(acc[3][1], s3, w1); fma4(acc[3][2], s3, w2);
        }
    }
    #pragma unroll
    for (int j = 0; j < 4; ++j) {
        int row = base + s + 32 * j;
        if (row >= NN) continue;
        float4 a0 = acc[j][0], a1 = acc[j][1], a2 = acc[j][2];
        if (MODE == 0) {
            a0.x = fmaxf(a0.x, 0.f); a0.y = fmaxf(a0.y, 0.f); a0.z = fmaxf(a0.z, 0.f); a0.w = fmaxf(a0.w, 0.f);
            a1.x = fmaxf(a1.x, 0.f); a1.y = fmaxf(a1.y, 0.f); a1.z = fmaxf(a1.z, 0.f); a1.w = fmaxf(a1.w, 0.f);
            a2.x = fmaxf(a2.x, 0.f); a2.y = fmaxf(a2.y, 0.f); a2.z = fmaxf(a2.z, 0.f); a2.w = fmaxf(a2.w, 0.f);
            __half2* o = Oh + ((size_t)row * DD + cg * 12) / 2;
            o[0] = __floats2half2_rn(a0.x, a0.y);
            o[1] = __floats2half2_rn(a0.z, a0.w);
            o[2] = __floats2half2_rn(a1.x, a1.y);
            o[3] = __floats2half2_rn(a1.z, a1.w);
            o[4] = __floats2half2_rn(a2.x, a2.y);
            o[5] = __floats2half2_rn(a2.z, a2.w);
        } else {
            float4* o = (float4*)(O + (size_t)row * DD + cg * 12);
            o[0] = a0; o[1] = a1; o[2] = a2;
        }
    }
}

// ---------------- pool stage A: per-graph striped partial sums ----------------
// grid = GG * 8 blocks, 384 threads = 96 dims x 4 row-stripes.
// block (g, s): rows i = start + (s*4 + t) + 32*j. LDS-reduce, one atomicAdd
// per dim into gsum[g][d].

__global__ __launch_bounds__(384) void k_pool_a(const float* __restrict__ P2,
                                                const int* __restrict__ batch,
                                                float* __restrict__ gsum) {
    int b = blockIdx.x;
    int g = b >> 3, s = b & 7;
    int tid = threadIdx.x;
    int d = tid % 96, t = tid / 96;
    int lo = 0, hi = NN;
    while (lo < hi) { int m = (lo + hi) >> 1; if (batch[m] < g) lo = m + 1; else hi = m; }
    int start = lo;
    lo = 0; hi = NN;
    while (lo < hi) { int m = (lo + hi) >> 1; if (batch[m] < g + 1) lo = m + 1; else hi = m; }
    int end = lo;
    float acc = 0.f;
    for (int i = start + s * 4 + t; i < end; i += 32) acc += P2[(size_t)i * DD + d];
    __shared__ float red[384];
    red[tid] = acc;
    __syncthreads();
    if (tid < 96) {
        float v = red[tid] + red[tid + 96] + red[tid + 192] + red[tid + 288];
        atomicAdd(&gsum[g * 96 + tid], v);
    }
}

// ---------------- pool stage B: outG = gsum @ W4 + cnt * b4 ----------------

__global__ __launch_bounds__(96) void k_pool_b(const float* __restrict__ gsum,
                                               const int* __restrict__ batch,
                                               const float* __restrict__ W4,
                                               const float* __restrict__ b4,
                                               float* __restrict__ outG) {
    int g = blockIdx.x, d = threadIdx.x;
    __shared__ float srow[96];
    srow[d] = gsum[g * 96 + d];
    int lo = 0, hi = NN;
    while (lo < hi) { int m = (lo + hi) >> 1; if (batch[m] < g) lo = m + 1; else hi = m; }
    int start = lo;
    lo = 0; hi = NN;
    while (lo < hi) { int m = (lo + hi) >> 1; if (batch[m] < g + 1) lo = m + 1; else hi = m; }
    int end = lo;
    __syncthreads();
    float o = (float)(end - start) * b4[d];
    #pragma unroll 8
    for (int k = 0; k < 96; ++k) o = fmaf(srow[k], W4[k * 96 + d], o);
    outG[g * 96 + d] = o;
}

// ---------------- launch ----------------

extern "C" void kernel_launch(void* const* d_in, const int* in_sizes, int n_in,
                              void* d_out, int out_size, void* d_ws, size_t ws_size,
                              hipStream_t stream) {
    const float* x  = (const float*)d_in[0];
    const float* W1 = (const float*)d_in[1];
    const float* b1 = (const float*)d_in[2];
    const float* W3 = (const float*)d_in[3];
    const float* b3 = (const float*)d_in[4];
    const float* W4 = (const float*)d_in[5];
    const float* b4 = (const float*)d_in[6];
    const float* ew = (const float*)d_in[7];
    const int* ei   = (const int*)d_in[8];
    const int* src  = ei;
    const int* dst  = ei + EE;
    const int* batch = (const int*)d_in[9];

    float* out_embed = (float*)d_out;
    float* out_graph = out_embed + (size_t)NN * DD;

    char* w = (char*)d_ws;
    auto alloc = [&](size_t bytes) { char* p = w; w += (bytes + 255) & ~(size_t)255; return p; };
    unsigned long long* packed = (unsigned long long*)alloc((size_t)NN * 8);
    unsigned int* rank = (unsigned int*)alloc((size_t)EE * 4);
    float* dinv    = (float*)alloc((size_t)NN * 4);
    int*   row_ptr = (int*)  alloc((size_t)(NN + 1) * 4);
    int*   bsums   = (int*)  alloc(256 * 4);
    float* gsum    = (float*)alloc((size_t)GG * DD * 4);
    int2*  csr     = (int2*) alloc((size_t)EE * 8);
    uint4* xh      = (uint4*)alloc((size_t)NN * DD * 2);   // fp16 x
    uint4* hh      = (uint4*)alloc((size_t)NN * DD * 2);   // fp16 h
    float* p1      = (float*)alloc((size_t)NN * DD * 4);   // A_hat @ x, reused as P2
    float* p2 = p1;   // p1 dead after first gemm; prop(h) writes here

    int nbN = (NN + 255) / 256;       // 196
    int nbE = (EE + 255) / 256;       // 3125

    hipMemsetAsync(packed, 0, (size_t)NN * 8, stream);
    hipMemsetAsync(gsum, 0, (size_t)GG * DD * 4, stream);
    k_hist<<<nbE, 256, 0, stream>>>(dst, ew, packed, rank);
    k_f2h<<<(NN * DD / 8 + 255) / 256, 256, 0, stream>>>((const float4*)x, xh);
    k_dinv<<<nbN, 256, 0, stream>>>(packed, dinv);
    k_reduce<<<nbN, 256, 0, stream>>>(packed, bsums);
    k_scan_bsums<<<1, 256, 0, stream>>>(bsums, nbN, row_ptr);
    k_scan_counts<<<nbN, 256, 0, stream>>>(packed, bsums, row_ptr);
    k_scatter<<<nbE, 256, 0, stream>>>(src, dst, ew, dinv, row_ptr, rank, csr);

    // P1 = A_hat @ x ; h = relu(P1 @ W1 + b1) [fp16]
    k_prop_h<<<(NN + 15) / 16, 192, 0, stream>>>(xh, csr, row_ptr, dinv, p1);
    k_gemm_bias<0><<<(NN + 127) / 128, 256, 0, stream>>>(p1, W1, b1, nullptr, (__half2*)hh);
    // P2 = A_hat @ h ; embed = P2 @ W3 + b3
    k_prop_h<<<(NN + 15) / 16, 192, 0, stream>>>(hh, csr, row_ptr, dinv, p2);
    k_gemm_bias<1><<<(NN + 127) / 128, 256, 0, stream>>>(p2, W3, b3, out_embed, nullptr);
    // out_graph = pool(P2) @ W4 + cnt * b4
    k_pool_a<<<GG * 8, 384, 0, stream>>>(p2, batch, gsum);
    k_pool_b<<<GG, 96, 0, stream>>>(gsum, batch, W4, b4, out_graph);
}

// Round 5
// 215.372 us; speedup vs baseline: 1.8950x; 1.0134x over previous
//
#include <hip/hip_runtime.h>
#include <hip/hip_fp16.h>

#define NN 50000
#define EE 800000
#define DD 96
#define GG 64
#define NC 24    // float4 chunks per 96-float row
#define NH 12    // uint4 (8-half) chunks per 96-half row

#define FPSCALE 16777216.0f           // 2^24 fixed-point for weight sums
#define MASK44 ((1ULL << 44) - 1)

// ---------------- zero workspace (replaces hipMemsetAsync fills) ----------------

__global__ void k_zero(unsigned long long* packed, float* gsum) {
    int i = blockIdx.x * 256 + threadIdx.x;
    if (i < NN) packed[i] = 0ULL;
    if (i < GG * DD) gsum[i] = 0.f;
}

// ---------------- CSR build ----------------
// One u64 atomic per edge: high 20 bits = count, low 44 bits = sum(w * 2^24).
// The returned old count is this edge's rank within its dst bucket -> the
// scatter pass needs no atomics at all.

__global__ void k_hist(const int* __restrict__ dst, const float* __restrict__ ew,
                       unsigned long long* packed, unsigned int* rank) {
    int e = blockIdx.x * 256 + threadIdx.x;
    if (e < EE) {
        unsigned long long q = (unsigned long long)(ew[e] * FPSCALE + 0.5f);
        unsigned long long old = atomicAdd(&packed[dst[e]], (1ULL << 44) | q);
        rank[e] = (unsigned int)(old >> 44);
    }
}

// dinv + per-block count sums in one pass over packed
__global__ void k_dinv_reduce(const unsigned long long* __restrict__ packed,
                              float* dinv, int* bsums) {
    __shared__ int s[256];
    int tid = threadIdx.x;
    int i = blockIdx.x * 256 + tid;
    unsigned long long p = (i < NN) ? packed[i] : 0ULL;
    if (i < NN) {
        float sum = (float)(p & MASK44) * (1.0f / FPSCALE);
        dinv[i] = rsqrtf(1.0f + sum);   // self-loop weight 1.0 included
    }
    s[tid] = (int)(p >> 44);
    __syncthreads();
    for (int off = 128; off > 0; off >>= 1) {
        if (tid < off) s[tid] += s[tid + off];
        __syncthreads();
    }
    if (tid == 0) bsums[blockIdx.x] = s[0];
}

__global__ void k_scan_bsums(int* bsums, int nb, int* row_ptr) {
    __shared__ int s[256];
    int tid = threadIdx.x;
    int v = (tid < nb) ? bsums[tid] : 0;
    s[tid] = v; __syncthreads();
    for (int off = 1; off < 256; off <<= 1) {
        int t = (tid >= off) ? s[tid - off] : 0;
        __syncthreads();
        s[tid] += t;
        __syncthreads();
    }
    if (tid < nb) bsums[tid] = s[tid] - v;   // exclusive
    if (tid == 0) row_ptr[NN] = EE;
}

__global__ void k_scan_counts(const unsigned long long* __restrict__ packed,
                              const int* __restrict__ bsums, int* row_ptr) {
    __shared__ int s[256];
    int tid = threadIdx.x;
    int i = blockIdx.x * 256 + tid;
    int v = (i < NN) ? (int)(packed[i] >> 44) : 0;
    s[tid] = v; __syncthreads();
    for (int off = 1; off < 256; off <<= 1) {
        int t = (tid >= off) ? s[tid - off] : 0;
        __syncthreads();
        s[tid] += t;
        __syncthreads();
    }
    if (i < NN) row_ptr[i] = bsums[blockIdx.x] + s[tid] - v;   // exclusive
}

__global__ void k_scatter(const int* __restrict__ src, const int* __restrict__ dst,
                          const float* __restrict__ ew, const float* __restrict__ dinv,
                          const int* __restrict__ row_ptr,
                          const unsigned int* __restrict__ rank, int2* csr) {
    int e = blockIdx.x * 256 + threadIdx.x;
    if (e < EE) {
        int s = src[e], d = dst[e];
        int p = row_ptr[d] + (int)rank[e];
        float w = dinv[s] * ew[e] * dinv[d];
        csr[p] = make_int2(s, __float_as_int(w));
    }
}

// ---------------- f32 -> fp16 table conversion ----------------

__global__ void k_f2h(const float4* __restrict__ in, uint4* __restrict__ out) {
    int i = blockIdx.x * 256 + threadIdx.x;
    if (i >= NN * DD / 8) return;
    float4 f0 = in[2 * i], f1 = in[2 * i + 1];
    __half2 h0 = __floats2half2_rn(f0.x, f0.y);
    __half2 h1 = __floats2half2_rn(f0.z, f0.w);
    __half2 h2 = __floats2half2_rn(f1.x, f1.y);
    __half2 h3 = __floats2half2_rn(f1.z, f1.w);
    uint4 o;
    o.x = *(unsigned int*)&h0; o.y = *(unsigned int*)&h1;
    o.z = *(unsigned int*)&h2; o.w = *(unsigned int*)&h3;
    out[i] = o;
}

// ---------------- propagation (CSR gather, fp16 rows): P = A_hat * T ----------------
// 192 threads = 16 nodes x 12 chunks of 8 halves. f32 accumulate, f32 output.

__device__ __forceinline__ void cvt8(uint4 v, float* f) {
    const __half2* h = (const __half2*)&v;
    #pragma unroll
    for (int k = 0; k < 4; ++k) {
        float2 t = __half22float2(h[k]);
        f[2 * k] = t.x; f[2 * k + 1] = t.y;
    }
}

__global__ __launch_bounds__(192) void k_prop_h(const uint4* __restrict__ Th,
                                                const int2* __restrict__ csr,
                                                const int* __restrict__ row_ptr,
                                                const float* __restrict__ dinv,
                                                float* __restrict__ P) {
    int tid = threadIdx.x;
    int node = blockIdx.x * 16 + tid / 12;
    int c = tid % 12;
    if (node >= NN) return;
    float di = dinv[node];
    float self = di * di;
    float f[8], acc[8];
    cvt8(Th[node * NH + c], f);
    #pragma unroll
    for (int j = 0; j < 8; ++j) acc[j] = self * f[j];
    int e0 = row_ptr[node], e1 = row_ptr[node + 1];
    for (int e = e0; e < e1; ++e) {
        int2 sw = csr[e];
        float w = __int_as_float(sw.y);
        cvt8(Th[sw.x * NH + c], f);
        #pragma unroll
        for (int j = 0; j < 8; ++j) acc[j] = fmaf(w, f[j], acc[j]);
    }
    float4* o = (float4*)(P + (size_t)node * DD + c * 8);
    o[0] = make_float4(acc[0], acc[1], acc[2], acc[3]);
    o[1] = make_float4(acc[4], acc[5], acc[6], acc[7]);
}

// ---------------- GEMM: O = act(X @ W + b)  (W in LDS) ----------------
// 256 threads; each thread: 4 rows x 12 cols. Block covers 128 rows.
// MODE 0: relu, fp16 output. MODE 1: plain, f32 output.

__device__ __forceinline__ void fma4(float4& a, float s, const float4 w) {
    a.x = fmaf(s, w.x, a.x); a.y = fmaf(s, w.y, a.y);
    a.z = fmaf(s, w.z, a.z); a.w = fmaf(s, w.w, a.w);
}

template<int MODE>
__global__ __launch_bounds__(256) void k_gemm_bias(const float* __restrict__ X,
                                                   const float* __restrict__ W,
                                                   const float* __restrict__ bias,
                                                   float* __restrict__ O,
                                                   __half2* __restrict__ Oh) {
    __shared__ float sW[DD * DD];
    int tid = threadIdx.x;
    for (int i = tid; i < DD * DD / 4; i += 256)
        ((float4*)sW)[i] = ((const float4*)W)[i];
    __syncthreads();
    int cg = tid & 7, s = tid >> 3;
    int base = blockIdx.x * 128;
    const float4* bv = (const float4*)bias + cg * 3;
    const float4* xr0; const float4* xr1; const float4* xr2; const float4* xr3;
    {
        int r0 = base + s;        int c0 = r0 < NN ? r0 : NN - 1;
        int r1 = base + s + 32;   int c1 = r1 < NN ? r1 : NN - 1;
        int r2 = base + s + 64;   int c2 = r2 < NN ? r2 : NN - 1;
        int r3 = base + s + 96;   int c3 = r3 < NN ? r3 : NN - 1;
        xr0 = (const float4*)(X + (size_t)c0 * DD);
        xr1 = (const float4*)(X + (size_t)c1 * DD);
        xr2 = (const float4*)(X + (size_t)c2 * DD);
        xr3 = (const float4*)(X + (size_t)c3 * DD);
    }
    float4 acc[4][3];
    #pragma unroll
    for (int j = 0; j < 4; ++j) { acc[j][0] = bv[0]; acc[j][1] = bv[1]; acc[j][2] = bv[2]; }

    #pragma unroll 2
    for (int k4 = 0; k4 < NC; ++k4) {
        float4 xv0 = xr0[k4], xv1 = xr1[k4], xv2 = xr2[k4], xv3 = xr3[k4];
        #pragma unroll
        for (int kk = 0; kk < 4; ++kk) {
            const float4* wr = (const float4*)&sW[(k4 * 4 + kk) * DD + cg * 12];
            float4 w0 = wr[0], w1 = wr[1], w2 = wr[2];
            float s0 = kk == 0 ? xv0.x : kk == 1 ? xv0.y : kk == 2 ? xv0.z : xv0.w;
            float s1 = kk == 0 ? xv1.x : kk == 1 ? xv1.y : kk == 2 ? xv1.z : xv1.w;
            float s2 = kk == 0 ? xv2.x : kk == 1 ? xv2.y : kk == 2 ? xv2.z : xv2.w;
            float s3 = kk == 0 ? xv3.x : kk == 1 ? xv3.y : kk == 2 ? xv3.z : xv3.w;
            fma4(acc[0][0], s0, w0); fma4(acc[0][1], s0, w1); fma4(acc[0][2], s0, w2);
            fma4(acc[1][0], s1, w0); fma4(acc[1][1], s1, w1); fma4(acc[1][2], s1, w2);
            fma4(acc[2][0], s2, w0); fma4(acc[2][1], s2, w1); fma4(acc[2][2], s2, w2);
            fma4(acc[3][0], s3, w0); fma4(acc[3][1], s3, w1); fma4(acc[3][2], s3, w2);
        }
    }
    #pragma unroll
    for (int j = 0; j < 4; ++j) {
        int row = base + s + 32 * j;
        if (row >= NN) continue;
        float4 a0 = acc[j][0], a1 = acc[j][1], a2 = acc[j][2];
        if (MODE == 0) {
            a0.x = fmaxf(a0.x, 0.f); a0.y = fmaxf(a0.y, 0.f); a0.z = fmaxf(a0.z, 0.f); a0.w = fmaxf(a0.w, 0.f);
            a1.x = fmaxf(a1.x, 0.f); a1.y = fmaxf(a1.y, 0.f); a1.z = fmaxf(a1.z, 0.f); a1.w = fmaxf(a1.w, 0.f);
            a2.x = fmaxf(a2.x, 0.f); a2.y = fmaxf(a2.y, 0.f); a2.z = fmaxf(a2.z, 0.f); a2.w = fmaxf(a2.w, 0.f);
            __half2* o = Oh + ((size_t)row * DD + cg * 12) / 2;
            o[0] = __floats2half2_rn(a0.x, a0.y);
            o[1] = __floats2half2_rn(a0.z, a0.w);
            o[2] = __floats2half2_rn(a1.x, a1.y);
            o[3] = __floats2half2_rn(a1.z, a1.w);
            o[4] = __floats2half2_rn(a2.x, a2.y);
            o[5] = __floats2half2_rn(a2.z, a2.w);
        } else {
            float4* o = (float4*)(O + (size_t)row * DD + cg * 12);
            o[0] = a0; o[1] = a1; o[2] = a2;
        }
    }
}

// ---------------- pool stage A: per-graph striped partial sums ----------------

__global__ __launch_bounds__(384) void k_pool_a(const float* __restrict__ P2,
                                                const int* __restrict__ batch,
                                                float* __restrict__ gsum) {
    int b = blockIdx.x;
    int g = b >> 3, s = b & 7;
    int tid = threadIdx.x;
    int d = tid % 96, t = tid / 96;
    int lo = 0, hi = NN;
    while (lo < hi) { int m = (lo + hi) >> 1; if (batch[m] < g) lo = m + 1; else hi = m; }
    int start = lo;
    lo = 0; hi = NN;
    while (lo < hi) { int m = (lo + hi) >> 1; if (batch[m] < g + 1) lo = m + 1; else hi = m; }
    int end = lo;
    float acc = 0.f;
    for (int i = start + s * 4 + t; i < end; i += 32) acc += P2[(size_t)i * DD + d];
    __shared__ float red[384];
    red[tid] = acc;
    __syncthreads();
    if (tid < 96) {
        float v = red[tid] + red[tid + 96] + red[tid + 192] + red[tid + 288];
        atomicAdd(&gsum[g * 96 + tid], v);
    }
}

// ---------------- pool stage B: outG = gsum @ W4 + cnt * b4 ----------------

__global__ __launch_bounds__(96) void k_pool_b(const float* __restrict__ gsum,
                                               const int* __restrict__ batch,
                                               const float* __restrict__ W4,
                                               const float* __restrict__ b4,
                                               float* __restrict__ outG) {
    int g = blockIdx.x, d = threadIdx.x;
    __shared__ float srow[96];
    srow[d] = gsum[g * 96 + d];
    int lo = 0, hi = NN;
    while (lo < hi) { int m = (lo + hi) >> 1; if (batch[m] < g) lo = m + 1; else hi = m; }
    int start = lo;
    lo = 0; hi = NN;
    while (lo < hi) { int m = (lo + hi) >> 1; if (batch[m] < g + 1) lo = m + 1; else hi = m; }
    int end = lo;
    __syncthreads();
    float o = (float)(end - start) * b4[d];
    #pragma unroll 8
    for (int k = 0; k < 96; ++k) o = fmaf(srow[k], W4[k * 96 + d], o);
    outG[g * 96 + d] = o;
}

// ---------------- launch ----------------

extern "C" void kernel_launch(void* const* d_in, const int* in_sizes, int n_in,
                              void* d_out, int out_size, void* d_ws, size_t ws_size,
                              hipStream_t stream) {
    const float* x  = (const float*)d_in[0];
    const float* W1 = (const float*)d_in[1];
    const float* b1 = (const float*)d_in[2];
    const float* W3 = (const float*)d_in[3];
    const float* b3 = (const float*)d_in[4];
    const float* W4 = (const float*)d_in[5];
    const float* b4 = (const float*)d_in[6];
    const float* ew = (const float*)d_in[7];
    const int* ei   = (const int*)d_in[8];
    const int* src  = ei;
    const int* dst  = ei + EE;
    const int* batch = (const int*)d_in[9];

    float* out_embed = (float*)d_out;
    float* out_graph = out_embed + (size_t)NN * DD;

    char* w = (char*)d_ws;
    auto alloc = [&](size_t bytes) { char* p = w; w += (bytes + 255) & ~(size_t)255; return p; };
    unsigned long long* packed = (unsigned long long*)alloc((size_t)NN * 8);
    unsigned int* rank = (unsigned int*)alloc((size_t)EE * 4);
    float* dinv    = (float*)alloc((size_t)NN * 4);
    int*   row_ptr = (int*)  alloc((size_t)(NN + 1) * 4);
    int*   bsums   = (int*)  alloc(256 * 4);
    float* gsum    = (float*)alloc((size_t)GG * DD * 4);
    int2*  csr     = (int2*) alloc((size_t)EE * 8);
    uint4* xh      = (uint4*)alloc((size_t)NN * DD * 2);   // fp16 x
    uint4* hh      = (uint4*)alloc((size_t)NN * DD * 2);   // fp16 h
    float* p1      = (float*)alloc((size_t)NN * DD * 4);   // A_hat @ x, reused as P2
    float* p2 = p1;   // p1 dead after first gemm; prop(h) writes here

    int nbN = (NN + 255) / 256;       // 196
    int nbE = (EE + 255) / 256;       // 3125

    k_zero<<<nbN, 256, 0, stream>>>(packed, gsum);
    k_hist<<<nbE, 256, 0, stream>>>(dst, ew, packed, rank);
    k_f2h<<<(NN * DD / 8 + 255) / 256, 256, 0, stream>>>((const float4*)x, xh);
    k_dinv_reduce<<<nbN, 256, 0, stream>>>(packed, dinv, bsums);
    k_scan_bsums<<<1, 256, 0, stream>>>(bsums, nbN, row_ptr);
    k_scan_counts<<<nbN, 256, 0, stream>>>(packed, bsums, row_ptr);
    k_scatter<<<nbE, 256, 0, stream>>>(src, dst, ew, dinv, row_ptr, rank, csr);

    // P1 = A_hat @ x ; h = relu(P1 @ W1 + b1) [fp16]
    k_prop_h<<<(NN + 15) / 16, 192, 0, stream>>>(xh, csr, row_ptr, dinv, p1);
    k_gemm_bias<0><<<(NN + 127) / 128, 256, 0, stream>>>(p1, W1, b1, nullptr, (__half2*)hh);
    // P2 = A_hat @ h ; embed = P2 @ W3 + b3
    k_prop_h<<<(NN + 15) / 16, 192, 0, stream>>>(hh, csr, row_ptr, dinv, p2);
    k_gemm_bias<1><<<(NN + 127) / 128, 256, 0, stream>>>(p2, W3, b3, out_embed, nullptr);
    // out_graph = pool(P2) @ W4 + cnt * b4
    k_pool_a<<<GG * 8, 384, 0, stream>>>(p2, batch, gsum);
    k_pool_b<<<GG, 96, 0, stream>>>(gsum, batch, W4, b4, out_graph);
}

// Round 6
// 209.237 us; speedup vs baseline: 1.9505x; 1.0293x over previous
//
#include <hip/hip_runtime.h>
#include <hip/hip_fp16.h>

#define NN 50000
#define EE 800000
#define DD 96
#define GG 64
#define NC 24    // float4 chunks per 96-float row
#define NH 12    // uint4 (8-half) chunks per 96-half row

#define FPSCALE 16777216.0f           // 2^24 fixed-point for weight sums
#define MASK44 ((1ULL << 44) - 1)
#define PSTR 8   // packed[] stride in u64 (64B per node -> no same-line atomic false sharing)

// ---------------- zero workspace + f32->fp16 conversion (fused) ----------------

__global__ void k_zero_f2h(unsigned long long* packed, float* gsum,
                           const float4* __restrict__ in, uint4* __restrict__ out) {
    int i = blockIdx.x * 256 + threadIdx.x;
    if (i < NN) packed[(size_t)i * PSTR] = 0ULL;
    if (i < GG * DD) gsum[i] = 0.f;
    if (i < NN * DD / 8) {
        float4 f0 = in[2 * i], f1 = in[2 * i + 1];
        __half2 h0 = __floats2half2_rn(f0.x, f0.y);
        __half2 h1 = __floats2half2_rn(f0.z, f0.w);
        __half2 h2 = __floats2half2_rn(f1.x, f1.y);
        __half2 h3 = __floats2half2_rn(f1.z, f1.w);
        uint4 o;
        o.x = *(unsigned int*)&h0; o.y = *(unsigned int*)&h1;
        o.z = *(unsigned int*)&h2; o.w = *(unsigned int*)&h3;
        out[i] = o;
    }
}

// ---------------- CSR build ----------------
// One u64 atomic per edge: high 20 bits = count, low 44 bits = sum(w * 2^24).
// packed[] padded to 1 counter per 64B line (PSTR) to kill line-level
// serialization at the memory-side atomic unit.

__global__ void k_hist(const int* __restrict__ dst, const float* __restrict__ ew,
                       unsigned long long* packed, unsigned int* rank) {
    int e = blockIdx.x * 256 + threadIdx.x;
    if (e < EE) {
        unsigned long long q = (unsigned long long)(ew[e] * FPSCALE + 0.5f);
        unsigned long long old = atomicAdd(&packed[(size_t)dst[e] * PSTR], (1ULL << 44) | q);
        rank[e] = (unsigned int)(old >> 44);
    }
}

// dinv + per-block count sums in one pass over packed
__global__ void k_dinv_reduce(const unsigned long long* __restrict__ packed,
                              float* dinv, int* bsums) {
    __shared__ int s[256];
    int tid = threadIdx.x;
    int i = blockIdx.x * 256 + tid;
    unsigned long long p = (i < NN) ? packed[(size_t)i * PSTR] : 0ULL;
    if (i < NN) {
        float sum = (float)(p & MASK44) * (1.0f / FPSCALE);
        dinv[i] = rsqrtf(1.0f + sum);   // self-loop weight 1.0 included
    }
    s[tid] = (int)(p >> 44);
    __syncthreads();
    for (int off = 128; off > 0; off >>= 1) {
        if (tid < off) s[tid] += s[tid + off];
        __syncthreads();
    }
    if (tid == 0) bsums[blockIdx.x] = s[0];
}

__global__ void k_scan_bsums(int* bsums, int nb, int* row_ptr) {
    __shared__ int s[256];
    int tid = threadIdx.x;
    int v = (tid < nb) ? bsums[tid] : 0;
    s[tid] = v; __syncthreads();
    for (int off = 1; off < 256; off <<= 1) {
        int t = (tid >= off) ? s[tid - off] : 0;
        __syncthreads();
        s[tid] += t;
        __syncthreads();
    }
    if (tid < nb) bsums[tid] = s[tid] - v;   // exclusive
    if (tid == 0) row_ptr[NN] = EE;
}

__global__ void k_scan_counts(const unsigned long long* __restrict__ packed,
                              const int* __restrict__ bsums, int* row_ptr) {
    __shared__ int s[256];
    int tid = threadIdx.x;
    int i = blockIdx.x * 256 + tid;
    int v = (i < NN) ? (int)(packed[(size_t)i * PSTR] >> 44) : 0;
    s[tid] = v; __syncthreads();
    for (int off = 1; off < 256; off <<= 1) {
        int t = (tid >= off) ? s[tid - off] : 0;
        __syncthreads();
        s[tid] += t;
        __syncthreads();
    }
    if (i < NN) row_ptr[i] = bsums[blockIdx.x] + s[tid] - v;   // exclusive
}

__global__ void k_scatter(const int* __restrict__ src, const int* __restrict__ dst,
                          const float* __restrict__ ew, const float* __restrict__ dinv,
                          const int* __restrict__ row_ptr,
                          const unsigned int* __restrict__ rank, int2* csr) {
    int e = blockIdx.x * 256 + threadIdx.x;
    if (e < EE) {
        int s = src[e], d = dst[e];
        int p = row_ptr[d] + (int)rank[e];
        float w = dinv[s] * ew[e] * dinv[d];
        csr[p] = make_int2(s, __float_as_int(w));
    }
}

// ---------------- propagation (CSR gather, fp16 rows): P = A_hat * T ----------------
// 192 threads = 16 nodes x 12 chunks of 8 halves. f32 accumulate, f32 output.

__device__ __forceinline__ void cvt8(uint4 v, float* f) {
    const __half2* h = (const __half2*)&v;
    #pragma unroll
    for (int k = 0; k < 4; ++k) {
        float2 t = __half22float2(h[k]);
        f[2 * k] = t.x; f[2 * k + 1] = t.y;
    }
}

__global__ __launch_bounds__(192) void k_prop_h(const uint4* __restrict__ Th,
                                                const int2* __restrict__ csr,
                                                const int* __restrict__ row_ptr,
                                                const float* __restrict__ dinv,
                                                float* __restrict__ P) {
    int tid = threadIdx.x;
    int node = blockIdx.x * 16 + tid / 12;
    int c = tid % 12;
    if (node >= NN) return;
    float di = dinv[node];
    float self = di * di;
    float f[8], acc[8];
    cvt8(Th[node * NH + c], f);
    #pragma unroll
    for (int j = 0; j < 8; ++j) acc[j] = self * f[j];
    int e0 = row_ptr[node], e1 = row_ptr[node + 1];
    for (int e = e0; e < e1; ++e) {
        int2 sw = csr[e];
        float w = __int_as_float(sw.y);
        cvt8(Th[sw.x * NH + c], f);
        #pragma unroll
        for (int j = 0; j < 8; ++j) acc[j] = fmaf(w, f[j], acc[j]);
    }
    float4* o = (float4*)(P + (size_t)node * DD + c * 8);
    o[0] = make_float4(acc[0], acc[1], acc[2], acc[3]);
    o[1] = make_float4(acc[4], acc[5], acc[6], acc[7]);
}

// ---------------- GEMM: O = act(X @ W + b)  (W in LDS) ----------------
// 256 threads; each thread: 4 rows x 12 cols. Block covers 128 rows.
// MODE 0: relu, fp16 output. MODE 1: plain, f32 output.

__device__ __forceinline__ void fma4(float4& a, float s, const float4 w) {
    a.x = fmaf(s, w.x, a.x); a.y = fmaf(s, w.y, a.y);
    a.z = fmaf(s, w.z, a.z); a.w = fmaf(s, w.w, a.w);
}

template<int MODE>
__global__ __launch_bounds__(256) void k_gemm_bias(const float* __restrict__ X,
                                                   const float* __restrict__ W,
                                                   const float* __restrict__ bias,
                                                   float* __restrict__ O,
                                                   __half2* __restrict__ Oh) {
    __shared__ float sW[DD * DD];
    int tid = threadIdx.x;
    for (int i = tid; i < DD * DD / 4; i += 256)
        ((float4*)sW)[i] = ((const float4*)W)[i];
    __syncthreads();
    int cg = tid & 7, s = tid >> 3;
    int base = blockIdx.x * 128;
    const float4* bv = (const float4*)bias + cg * 3;
    const float4* xr0; const float4* xr1; const float4* xr2; const float4* xr3;
    {
        int r0 = base + s;        int c0 = r0 < NN ? r0 : NN - 1;
        int r1 = base + s + 32;   int c1 = r1 < NN ? r1 : NN - 1;
        int r2 = base + s + 64;   int c2 = r2 < NN ? r2 : NN - 1;
        int r3 = base + s + 96;   int c3 = r3 < NN ? r3 : NN - 1;
        xr0 = (const float4*)(X + (size_t)c0 * DD);
        xr1 = (const float4*)(X + (size_t)c1 * DD);
        xr2 = (const float4*)(X + (size_t)c2 * DD);
        xr3 = (const float4*)(X + (size_t)c3 * DD);
    }
    float4 acc[4][3];
    #pragma unroll
    for (int j = 0; j < 4; ++j) { acc[j][0] = bv[0]; acc[j][1] = bv[1]; acc[j][2] = bv[2]; }

    #pragma unroll 2
    for (int k4 = 0; k4 < NC; ++k4) {
        float4 xv0 = xr0[k4], xv1 = xr1[k4], xv2 = xr2[k4], xv3 = xr3[k4];
        #pragma unroll
        for (int kk = 0; kk < 4; ++kk) {
            const float4* wr = (const float4*)&sW[(k4 * 4 + kk) * DD + cg * 12];
            float4 w0 = wr[0], w1 = wr[1], w2 = wr[2];
            float s0 = kk == 0 ? xv0.x : kk == 1 ? xv0.y : kk == 2 ? xv0.z : xv0.w;
            float s1 = kk == 0 ? xv1.x : kk == 1 ? xv1.y : kk == 2 ? xv1.z : xv1.w;
            float s2 = kk == 0 ? xv2.x : kk == 1 ? xv2.y : kk == 2 ? xv2.z : xv2.w;
            float s3 = kk == 0 ? xv3.x : kk == 1 ? xv3.y : kk == 2 ? xv3.z : xv3.w;
            fma4(acc[0][0], s0, w0); fma4(acc[0][1], s0, w1); fma4(acc[0][2], s0, w2);
            fma4(acc[1][0], s1, w0); fma4(acc[1][1], s1, w1); fma4(acc[1][2], s1, w2);
            fma4(acc[2][0], s2, w0); fma4(acc[2][1], s2, w1); fma4(acc[2][2], s2, w2);
            fma4(acc[3][0], s3, w0); fma4(acc[3][1], s3, w1); fma4(acc[3][2], s3, w2);
        }
    }
    #pragma unroll
    for (int j = 0; j < 4; ++j) {
        int row = base + s + 32 * j;
        if (row >= NN) continue;
        float4 a0 = acc[j][0], a1 = acc[j][1], a2 = acc[j][2];
        if (MODE == 0) {
            a0.x = fmaxf(a0.x, 0.f); a0.y = fmaxf(a0.y, 0.f); a0.z = fmaxf(a0.z, 0.f); a0.w = fmaxf(a0.w, 0.f);
            a1.x = fmaxf(a1.x, 0.f); a1.y = fmaxf(a1.y, 0.f); a1.z = fmaxf(a1.z, 0.f); a1.w = fmaxf(a1.w, 0.f);
            a2.x = fmaxf(a2.x, 0.f); a2.y = fmaxf(a2.y, 0.f); a2.z = fmaxf(a2.z, 0.f); a2.w = fmaxf(a2.w, 0.f);
            __half2* o = Oh + ((size_t)row * DD + cg * 12) / 2;
            o[0] = __floats2half2_rn(a0.x, a0.y);
            o[1] = __floats2half2_rn(a0.z, a0.w);
            o[2] = __floats2half2_rn(a1.x, a1.y);
            o[3] = __floats2half2_rn(a1.z, a1.w);
            o[4] = __floats2half2_rn(a2.x, a2.y);
            o[5] = __floats2half2_rn(a2.z, a2.w);
        } else {
            float4* o = (float4*)(O + (size_t)row * DD + cg * 12);
            o[0] = a0; o[1] = a1; o[2] = a2;
        }
    }
}

// ---------------- pool stage A: per-graph striped partial sums ----------------

__global__ __launch_bounds__(384) void k_pool_a(const float* __restrict__ P2,
                                                const int* __restrict__ batch,
                                                float* __restrict__ gsum) {
    int b = blockIdx.x;
    int g = b >> 3, s = b & 7;
    int tid = threadIdx.x;
    int d = tid % 96, t = tid / 96;
    int lo = 0, hi = NN;
    while (lo < hi) { int m = (lo + hi) >> 1; if (batch[m] < g) lo = m + 1; else hi = m; }
    int start = lo;
    lo = 0; hi = NN;
    while (lo < hi) { int m = (lo + hi) >> 1; if (batch[m] < g + 1) lo = m + 1; else hi = m; }
    int end = lo;
    float acc = 0.f;
    for (int i = start + s * 4 + t; i < end; i += 32) acc += P2[(size_t)i * DD + d];
    __shared__ float red[384];
    red[tid] = acc;
    __syncthreads();
    if (tid < 96) {
        float v = red[tid] + red[tid + 96] + red[tid + 192] + red[tid + 288];
        atomicAdd(&gsum[g * 96 + tid], v);
    }
}

// ---------------- pool stage B: outG = gsum @ W4 + cnt * b4 ----------------

__global__ __launch_bounds__(96) void k_pool_b(const float* __restrict__ gsum,
                                               const int* __restrict__ batch,
                                               const float* __restrict__ W4,
                                               const float* __restrict__ b4,
                                               float* __restrict__ outG) {
    int g = blockIdx.x, d = threadIdx.x;
    __shared__ float srow[96];
    srow[d] = gsum[g * 96 + d];
    int lo = 0, hi = NN;
    while (lo < hi) { int m = (lo + hi) >> 1; if (batch[m] < g) lo = m + 1; else hi = m; }
    int start = lo;
    lo = 0; hi = NN;
    while (lo < hi) { int m = (lo + hi) >> 1; if (batch[m] < g + 1) lo = m + 1; else hi = m; }
    int end = lo;
    __syncthreads();
    float o = (float)(end - start) * b4[d];
    #pragma unroll 8
    for (int k = 0; k < 96; ++k) o = fmaf(srow[k], W4[k * 96 + d], o);
    outG[g * 96 + d] = o;
}

// ---------------- launch ----------------

extern "C" void kernel_launch(void* const* d_in, const int* in_sizes, int n_in,
                              void* d_out, int out_size, void* d_ws, size_t ws_size,
                              hipStream_t stream) {
    const float* x  = (const float*)d_in[0];
    const float* W1 = (const float*)d_in[1];
    const float* b1 = (const float*)d_in[2];
    const float* W3 = (const float*)d_in[3];
    const float* b3 = (const float*)d_in[4];
    const float* W4 = (const float*)d_in[5];
    const float* b4 = (const float*)d_in[6];
    const float* ew = (const float*)d_in[7];
    const int* ei   = (const int*)d_in[8];
    const int* src  = ei;
    const int* dst  = ei + EE;
    const int* batch = (const int*)d_in[9];

    float* out_embed = (float*)d_out;
    float* out_graph = out_embed + (size_t)NN * DD;

    char* w = (char*)d_ws;
    auto alloc = [&](size_t bytes) { char* p = w; w += (bytes + 255) & ~(size_t)255; return p; };
    unsigned long long* packed = (unsigned long long*)alloc((size_t)NN * 8 * PSTR);
    unsigned int* rank = (unsigned int*)alloc((size_t)EE * 4);
    float* dinv    = (float*)alloc((size_t)NN * 4);
    int*   row_ptr = (int*)  alloc((size_t)(NN + 1) * 4);
    int*   bsums   = (int*)  alloc(256 * 4);
    float* gsum    = (float*)alloc((size_t)GG * DD * 4);
    int2*  csr     = (int2*) alloc((size_t)EE * 8);
    uint4* xh      = (uint4*)alloc((size_t)NN * DD * 2);   // fp16 x
    uint4* hh      = (uint4*)alloc((size_t)NN * DD * 2);   // fp16 h
    float* p1      = (float*)alloc((size_t)NN * DD * 4);   // A_hat @ x, reused as P2
    float* p2 = p1;   // p1 dead after first gemm; prop(h) writes here

    int nbN = (NN + 255) / 256;       // 196
    int nbE = (EE + 255) / 256;       // 3125

    k_zero_f2h<<<(NN * DD / 8 + 255) / 256, 256, 0, stream>>>(packed, gsum, (const float4*)x, xh);
    k_hist<<<nbE, 256, 0, stream>>>(dst, ew, packed, rank);
    k_dinv_reduce<<<nbN, 256, 0, stream>>>(packed, dinv, bsums);
    k_scan_bsums<<<1, 256, 0, stream>>>(bsums, nbN, row_ptr);
    k_scan_counts<<<nbN, 256, 0, stream>>>(packed, bsums, row_ptr);
    k_scatter<<<nbE, 256, 0, stream>>>(src, dst, ew, dinv, row_ptr, rank, csr);

    // P1 = A_hat @ x ; h = relu(P1 @ W1 + b1) [fp16]
    k_prop_h<<<(NN + 15) / 16, 192, 0, stream>>>(xh, csr, row_ptr, dinv, p1);
    k_gemm_bias<0><<<(NN + 127) / 128, 256, 0, stream>>>(p1, W1, b1, nullptr, (__half2*)hh);
    // P2 = A_hat @ h ; embed = P2 @ W3 + b3
    k_prop_h<<<(NN + 15) / 16, 192, 0, stream>>>(hh, csr, row_ptr, dinv, p2);
    k_gemm_bias<1><<<(NN + 127) / 128, 256, 0, stream>>>(p2, W3, b3, out_embed, nullptr);
    // out_graph = pool(P2) @ W4 + cnt * b4
    k_pool_a<<<GG * 8, 384, 0, stream>>>(p2, batch, gsum);
    k_pool_b<<<GG, 96, 0, stream>>>(gsum, batch, W4, b4, out_graph);
}